// Round 3
// baseline (190.016 us; speedup 1.0000x reference)
//
#include <hip/hip_runtime.h>

// OptimizedLinear: out = x@W^T + bias - lr[:,None]*(x@G^T + bias_grad)
// B=4096, IN=OUT=2048, fp32 in/out. bf16 MFMA fused dual-accumulator GEMM.
//
// Round 10: fragment-level software pipeline. R7/R8/R9 all sit at MfmaUtil
// 34-39% because reads-for-subtile-p complete before MFMA-of-subtile-p in
// every wave (R9's barriers made it strict). Per-tile cycles = MFMA(2483) +
// LDS(~2200) SERIAL. Fix: 4 register-subtiles per K-tile; in phase p issue
// ds_reads for subtile p+1, then MFMA subtile p (frag double-buffer). The
// wait before each MFMA is a compiler-counted lgkmcnt(N_next) -> each MFMA
// cluster covers the next subtile's LDS service. Cross-tile readahead at
// phase 3 via publish barrier at phase-2-end (vmcnt(0) has 2 phases cover).
// 2 barriers/tile. Per-acc update order unchanged -> absmax 0.03125.
//
// Lessons carried: granule-XOR layout conflict-free (R2-R9, BANK_CONFLICT=0);
// scattered per-wave A-loads poison drains (R6); 256-reg acc spills (R5,
// tripwire WRITE_SIZE >> 45MB); occupancy not the lever (R4); counted vmcnt
// alone null (R8); per-phase barrier lockstep hurts (R9: -9%).

typedef unsigned short ushort_t;
typedef __attribute__((ext_vector_type(8))) short short8;       // 8 bf16 = 4 VGPR
typedef __attribute__((ext_vector_type(8))) unsigned short ushort8;
typedef __attribute__((ext_vector_type(4))) float f32x4;

#define GPTR(p) ((const __attribute__((address_space(1))) void*)(p))
#define LPTR(p) ((__attribute__((address_space(3))) void*)(p))

static constexpr int Kdim = 2048;
static constexpr int Ndim = 2048;
static constexpr int BK   = 64;
static constexpr int BM   = 256;
static constexpr int BN   = 128;
static constexpr int NT   = Kdim / BK;   // 32 K-tiles

__device__ __forceinline__ unsigned short f2bf(float f) {
    union { float f; unsigned u; } c; c.f = f;
    unsigned u = c.u;
    unsigned r = (u + 0x7fffu + ((u >> 16) & 1u)) >> 16;  // RNE
    return (unsigned short)r;
}

// One launch converts x (uX ushort8-units), W (uW), G (uW). Unit = 8 elems.
__global__ void cvt_all_kernel(const float* __restrict__ x,
                               const float* __restrict__ W,
                               const float* __restrict__ G,
                               ushort_t* __restrict__ xb,
                               ushort_t* __restrict__ wb,
                               ushort_t* __restrict__ gb,
                               int uX, int uW) {
    int u = blockIdx.x * blockDim.x + threadIdx.x;
    const float* src; ushort_t* dst;
    if (u < uX)            { src = x; dst = xb; }
    else if (u < uX + uW)  { src = W; dst = wb; u -= uX; }
    else                   { src = G; dst = gb; u -= uX + uW; }
    int i = u * 8;
    float4 a = *(const float4*)(src + i);
    float4 b = *(const float4*)(src + i + 4);
    ushort8 r;
    r[0] = f2bf(a.x); r[1] = f2bf(a.y); r[2] = f2bf(a.z); r[3] = f2bf(a.w);
    r[4] = f2bf(b.x); r[5] = f2bf(b.y); r[6] = f2bf(b.z); r[7] = f2bf(b.w);
    *(ushort8*)(dst + i) = r;
}

// ---- fused dual GEMM, 256x128 tile, BK=64, 8 waves, frag-pipelined ----
// 512 threads = 8 waves (4 M x 2 N), each wave 64x64 = 4x4 MFMA tiles, dual
// acc. LDS: A 256x64, W/G 128x64 bf16, double-buffered: 128 KB (1 block/CU).
// Granule (row r, g=k/8) lives at slot r*8 + (g ^ (r&7)); swizzle applied on
// the GLOBAL fetch address (LDS dst is HW-forced to base + lane*16).
// Fragment read: addr = row*64 + ((j*4+quad) ^ (row&7))*8 -> conflict-free
// (0 bank conflicts measured across R2-R9 with this exact layout).
//
// Subtiles per K-tile: s0=(j0,h0) 8 reads, s1=(j0,h1) 4, s2=(j1,h0) 8,
// s3=(j1,h1) 4; each subtile = 16 MFMA. Phase p: {issue reads s(p+1);
// MFMA s(p)}. Frag buffers: af[2] (per j), wf/gf ping-pong (per h-slot).
__global__ __launch_bounds__(512, 2) void fused_gemm_kernel(
    const ushort_t* __restrict__ xb,   // [4096, 2048] bf16
    const ushort_t* __restrict__ wb,   // [2048, 2048] bf16
    const ushort_t* __restrict__ gb,   // [2048, 2048] bf16
    const float* __restrict__ bias,    // [2048]
    const float* __restrict__ bgrad,   // [2048]
    const float* __restrict__ lr,      // [4096]
    float* __restrict__ out)           // [4096, 2048] fp32
{
    __shared__ ushort_t As[2][BM * BK];  // 2 x 32 KB
    __shared__ ushort_t Ws[2][BN * BK];  // 2 x 16 KB
    __shared__ ushort_t Gs[2][BN * BK];  // 2 x 16 KB

    const int t    = threadIdx.x;
    const int wave = t >> 6;
    const int lane = t & 63;
    const int wm   = (wave >> 1) * 64;   // 0,64,128,192
    const int wn   = (wave & 1) * 64;    // 0,64

    // XCD-chunked swizzle: 256 blocks, 8 XCDs, 32 blocks/XCD = 2 by-rows x 16 bx.
    const int bid = blockIdx.y * 16 + blockIdx.x;
    const int swz = (bid & 7) * 32 + (bid >> 3);
    const int by  = swz >> 4;   // M tile (0..15)
    const int bx  = swz & 15;   // N tile (0..15)

    const int fr   = lane & 15;    // fragment row
    const int quad = lane >> 4;    // k-granule select (0..3)

    f32x4 accB[4][4] = {};
    f32x4 accP[4][4] = {};

    // --- staging addressing ---
    // A: 2048 slots of 16B (4 issues/thread). W/G: 1024 slots (2 issues each).
    // slot s: row = s>>3, fetched granule q' = (s&7) ^ (row&7)
    const ushort_t* gA[4]; int dA[4];
#pragma unroll
    for (int i = 0; i < 4; ++i) {
        int s   = i * 512 + t;
        int row = s >> 3;
        int q   = ((s & 7) ^ (row & 7)) * 8;
        gA[i] = xb + (size_t)(by * BM + row) * Kdim + q;
        dA[i] = (i * 512 + wave * 64) * 8;   // wave-uniform base; HW adds lane*16B
    }
    const ushort_t* gW[2]; const ushort_t* gG[2]; int dW[2];
#pragma unroll
    for (int i = 0; i < 2; ++i) {
        int s   = i * 512 + t;
        int row = s >> 3;
        int q   = ((s & 7) ^ (row & 7)) * 8;
        gW[i] = wb + (size_t)(bx * BN + row) * Kdim + q;
        gG[i] = gb + (size_t)(bx * BN + row) * Kdim + q;
        dW[i] = (i * 512 + wave * 64) * 8;
    }

    // fragment registers: af per j; wf/gf ping-pong per subtile parity
    short8 af[2][4], wf[2][2], gf[2][2];

    // 8 global_load_lds per thread per K-tile (4 A + 2 W + 2 G)
#define STAGE(B, K0) do {                                                         \
    _Pragma("unroll")                                                             \
    for (int i = 0; i < 4; ++i)                                                   \
        __builtin_amdgcn_global_load_lds(GPTR(gA[i] + (K0)),                      \
                                         LPTR(&As[B][dA[i]]), 16, 0, 0);          \
    _Pragma("unroll")                                                             \
    for (int i = 0; i < 2; ++i) {                                                 \
        __builtin_amdgcn_global_load_lds(GPTR(gW[i] + (K0)),                      \
                                         LPTR(&Ws[B][dW[i]]), 16, 0, 0);          \
        __builtin_amdgcn_global_load_lds(GPTR(gG[i] + (K0)),                      \
                                         LPTR(&Gs[B][dW[i]]), 16, 0, 0);          \
    }                                                                             \
} while (0)

#define KC(J) ((((J) * 4 + quad) ^ (fr & 7)) * 8)

    // 4 A-fragment reads for k-half J
#define RD_AF(B, J) do {                                                          \
    const int kc_ = KC(J);                                                        \
    _Pragma("unroll")                                                             \
    for (int mt = 0; mt < 4; ++mt)                                                \
        af[J][mt] = *(const short8*)(&As[B][(wm + mt * 16 + fr) * BK + kc_]);     \
} while (0)

    // 2 W + 2 G fragment reads for (J, nt-half H) into ping-pong slot S
#define RD_WG(B, J, H, S) do {                                                    \
    const int kc_ = KC(J);                                                        \
    _Pragma("unroll")                                                             \
    for (int i = 0; i < 2; ++i) {                                                 \
        const int nt = (H) * 2 + i;                                               \
        wf[S][i] = *(const short8*)(&Ws[B][(wn + nt * 16 + fr) * BK + kc_]);      \
        gf[S][i] = *(const short8*)(&Gs[B][(wn + nt * 16 + fr) * BK + kc_]);      \
    }                                                                             \
} while (0)

    // 16-MFMA cluster: k-half J, nt-half H, slot S. Per-acc order == R7/R8/R9.
#define MFMA16(J, H, S) do {                                                      \
    __builtin_amdgcn_s_setprio(1);                                                \
    _Pragma("unroll")                                                             \
    for (int mt = 0; mt < 4; ++mt) {                                              \
        _Pragma("unroll")                                                         \
        for (int i = 0; i < 2; ++i) {                                             \
            const int nt = (H) * 2 + i;                                           \
            accB[mt][nt] = __builtin_amdgcn_mfma_f32_16x16x32_bf16(               \
                af[J][mt], wf[S][i], accB[mt][nt], 0, 0, 0);                      \
            accP[mt][nt] = __builtin_amdgcn_mfma_f32_16x16x32_bf16(               \
                af[J][mt], gf[S][i], accP[mt][nt], 0, 0, 0);                      \
        }                                                                         \
    }                                                                             \
    __builtin_amdgcn_s_setprio(0);                                                \
} while (0)

#define BARRIER() __builtin_amdgcn_s_barrier()
#define FENCE()   __builtin_amdgcn_sched_barrier(0)
#define VMCNT0()  asm volatile("s_waitcnt vmcnt(0)" ::: "memory")

    // One K-tile on buffer B. Entry state: subtile s0(t) reads in flight
    // (issued last phase of previous tile); buf B published.
    // RA: do cross-tile readahead of s0(t+1) from B^1 in phase 3.
#define KTILE(B, K0NEXT) do {                                                     \
    /* p0 */                                                                      \
    STAGE(B ^ 1, K0NEXT);                                                         \
    RD_WG(B, 0, 1, 1);                      /* s1 reads (4) */                    \
    FENCE();                                                                      \
    MFMA16(0, 0, 0);                        /* s0: waits its own reads only */    \
    FENCE();                                                                      \
    /* p1 */                                                                      \
    RD_AF(B, 1); RD_WG(B, 1, 0, 0);         /* s2 reads (8) */                    \
    FENCE();                                                                      \
    MFMA16(0, 1, 1);                        /* s1 */                              \
    FENCE();                                                                      \
    /* p2 */                                                                      \
    RD_WG(B, 1, 1, 1);                      /* s3 reads (4) */                    \
    FENCE();                                                                      \
    MFMA16(1, 0, 0);                        /* s2 */                              \
    FENCE();                                                                      \
    VMCNT0();                               /* t+1 landed (2 phases cover) */     \
    BARRIER();                              /* publish B^1 */                     \
    FENCE();                                                                      \
    /* p3 */                                                                      \
    RD_AF(B ^ 1, 0); RD_WG(B ^ 1, 0, 0, 0); /* s0(t+1) readahead (8) */           \
    FENCE();                                                                      \
    MFMA16(1, 1, 1);                        /* s3 */                              \
    FENCE();                                                                      \
    BARRIER();                              /* all reads of B done -> B free */   \
    FENCE();                                                                      \
} while (0)

    // Last tile: no stage, no readahead, no trailing barriers.
#define KTILE_LAST(B) do {                                                        \
    RD_WG(B, 0, 1, 1); FENCE(); MFMA16(0, 0, 0); FENCE();                         \
    RD_AF(B, 1); RD_WG(B, 1, 0, 0); FENCE(); MFMA16(0, 1, 1); FENCE();            \
    RD_WG(B, 1, 1, 1); FENCE(); MFMA16(1, 0, 0); FENCE();                         \
    MFMA16(1, 1, 1);                                                              \
} while (0)

    // prologue: stage tile 0 into buf0, publish, issue s0(tile0) reads
    STAGE(0, 0);
    VMCNT0();
    BARRIER();
    FENCE();
    RD_AF(0, 0); RD_WG(0, 0, 0, 0);
    FENCE();

#pragma unroll 1
    for (int t2 = 0; t2 < NT - 2; t2 += 2) {
        KTILE(0, (t2 + 1) * BK);
        KTILE(1, (t2 + 2) * BK);
    }
    KTILE(0, (NT - 1) * BK);   // tile 30: stages + reads ahead into tile 31
    KTILE_LAST(1);             // tile 31

#undef STAGE
#undef RD_AF
#undef RD_WG
#undef MFMA16
#undef KTILE
#undef KTILE_LAST
#undef KC
#undef VMCNT0
#undef FENCE
#undef BARRIER

    // --- epilogue: out = base + bias[n] - lr[m]*(pert + bgrad[n]) ---
    // C/D layout: col = lane&15, row = quad*4 + reg  (verified R2-R9)
    const int col = fr;
    const int gmb = by * BM + wm;
    const int gnb = bx * BN + wn;

    float lrv[4][4];
#pragma unroll
    for (int mt = 0; mt < 4; ++mt)
#pragma unroll
        for (int i = 0; i < 4; ++i)
            lrv[mt][i] = lr[gmb + mt * 16 + quad * 4 + i];

#pragma unroll
    for (int nt = 0; nt < 4; ++nt) {
        const int gn = gnb + nt * 16 + col;
        const float bn = bias[gn];
        const float bg = bgrad[gn];
#pragma unroll
        for (int mt = 0; mt < 4; ++mt) {
#pragma unroll
            for (int i = 0; i < 4; ++i) {
                const int gm = gmb + mt * 16 + quad * 4 + i;
                float v = accB[mt][nt][i] + bn - lrv[mt][i] * (accP[mt][nt][i] + bg);
                __builtin_nontemporal_store(v, out + (size_t)gm * Ndim + gn);
            }
        }
    }
}

extern "C" void kernel_launch(void* const* d_in, const int* in_sizes, int n_in,
                              void* d_out, int out_size, void* d_ws, size_t ws_size,
                              hipStream_t stream) {
    const float* x     = (const float*)d_in[0];  // [4096, 2048]
    const float* W     = (const float*)d_in[1];  // [2048, 2048]
    const float* bias  = (const float*)d_in[2];  // [2048]
    const float* G     = (const float*)d_in[3];  // [2048, 2048]
    const float* bgrad = (const float*)d_in[4];  // [2048]
    const float* lr    = (const float*)d_in[5];  // [4096]
    float* out = (float*)d_out;

    const int nX = 4096 * 2048;
    const int nW = 2048 * 2048;

    ushort_t* xb = (ushort_t*)d_ws;
    ushort_t* wb = xb + nX;
    ushort_t* gb = wb + nW;

    const int uX = nX / 8, uW = nW / 8;
    const int totalU = uX + 2 * uW;               // 2,097,152
    cvt_all_kernel<<<totalU / 256, 256, 0, stream>>>(x, W, G, xb, wb, gb, uX, uW);

    dim3 grid(16, 16);   // N tiles x M tiles = 256 blocks = 1/CU
    fused_gemm_kernel<<<grid, 512, 0, stream>>>(xb, wb, gb, bias, bgrad, lr, out);
}

// Round 4
// 179.571 us; speedup vs baseline: 1.0582x; 1.0582x over previous
//
#include <hip/hip_runtime.h>

// OptimizedLinear: out = x@W^T + bias - lr[:,None]*(x@G^T + bias_grad)
// B=4096, IN=OUT=2048, fp32 in/out. bf16 MFMA fused dual-accumulator GEMM.
//
// Round 11: m201-faithful 4-phase schedule. Fence-count autopsy of R8/R9/R10
// (72/79/101 us at 2/~20/~40 sched_barriers + R10 spill) says sched fences
// are poison (m141) and frag double-buffering spills (R5/R10). The m201
// template reaches 62% MfmaUtil at IDENTICAL per-wave geometry (64 MFMA /
// 24 ds_read per K-tile per wave) using BARRIERS as the scheduler:
//   per phase: {ds_read subtile; 2-3 global_load_lds; s_barrier;
//               lgkmcnt(0)+1 fence (rule 18); setprio(1); 16 MFMA;
//               setprio(0); s_barrier}
// 4 phases/K-tile, staging spread 3/3/2/0, vmcnt(0) inside phase 3 (>=1
// phase of cover for the last pair), 8 barriers/tile, 4 fences/tile, NO
// frag ping-pong (VGPR budget == R8, no spill). Per-acc update order
// unchanged -> absmax 0.03125 exactly.
//
// Lessons carried: granule-XOR layout conflict-free (R2-R10, BANK_CONFLICT
// =0); scattered per-wave A-loads poison drains (R6); frag ping-pong spills
// at 2 waves/SIMD (R10, tripwire WRITE_SIZE >> 45MB); sched_barrier(0)
// beyond rule-18 minimum regresses (R9/R10 = m141); counted vmcnt alone
// null (R8); occupancy not the lever (R4).

typedef unsigned short ushort_t;
typedef __attribute__((ext_vector_type(8))) short short8;       // 8 bf16 = 4 VGPR
typedef __attribute__((ext_vector_type(8))) unsigned short ushort8;
typedef __attribute__((ext_vector_type(4))) float f32x4;

#define GPTR(p) ((const __attribute__((address_space(1))) void*)(p))
#define LPTR(p) ((__attribute__((address_space(3))) void*)(p))

static constexpr int Kdim = 2048;
static constexpr int Ndim = 2048;
static constexpr int BK   = 64;
static constexpr int BM   = 256;
static constexpr int BN   = 128;
static constexpr int NT   = Kdim / BK;   // 32 K-tiles

__device__ __forceinline__ unsigned short f2bf(float f) {
    union { float f; unsigned u; } c; c.f = f;
    unsigned u = c.u;
    unsigned r = (u + 0x7fffu + ((u >> 16) & 1u)) >> 16;  // RNE
    return (unsigned short)r;
}

// One launch converts x (uX ushort8-units), W (uW), G (uW). Unit = 8 elems.
__global__ void cvt_all_kernel(const float* __restrict__ x,
                               const float* __restrict__ W,
                               const float* __restrict__ G,
                               ushort_t* __restrict__ xb,
                               ushort_t* __restrict__ wb,
                               ushort_t* __restrict__ gb,
                               int uX, int uW) {
    int u = blockIdx.x * blockDim.x + threadIdx.x;
    const float* src; ushort_t* dst;
    if (u < uX)            { src = x; dst = xb; }
    else if (u < uX + uW)  { src = W; dst = wb; u -= uX; }
    else                   { src = G; dst = gb; u -= uX + uW; }
    int i = u * 8;
    float4 a = *(const float4*)(src + i);
    float4 b = *(const float4*)(src + i + 4);
    ushort8 r;
    r[0] = f2bf(a.x); r[1] = f2bf(a.y); r[2] = f2bf(a.z); r[3] = f2bf(a.w);
    r[4] = f2bf(b.x); r[5] = f2bf(b.y); r[6] = f2bf(b.z); r[7] = f2bf(b.w);
    *(ushort8*)(dst + i) = r;
}

// ---- fused dual GEMM, 256x128 tile, BK=64, 8 waves, 4-phase barriered ----
// 512 threads = 8 waves (4 M x 2 N), each wave 64x64 = 4x4 MFMA tiles, dual
// acc. LDS: A 256x64, W/G 128x64 bf16, double-buffered: 128 KB (1 block/CU).
// Granule (row r, g=k/8) lives at slot r*8 + (g ^ (r&7)); swizzle applied on
// the GLOBAL fetch address (LDS dst is HW-forced to base + lane*16).
// Fragment read: addr = row*64 + ((j*4+quad) ^ (row&7))*8 -> conflict-free
// (0 bank conflicts measured across R2-R10 with this exact layout).
__global__ __launch_bounds__(512, 2) void fused_gemm_kernel(
    const ushort_t* __restrict__ xb,   // [4096, 2048] bf16
    const ushort_t* __restrict__ wb,   // [2048, 2048] bf16
    const ushort_t* __restrict__ gb,   // [2048, 2048] bf16
    const float* __restrict__ bias,    // [2048]
    const float* __restrict__ bgrad,   // [2048]
    const float* __restrict__ lr,      // [4096]
    float* __restrict__ out)           // [4096, 2048] fp32
{
    __shared__ ushort_t As[2][BM * BK];  // 2 x 32 KB
    __shared__ ushort_t Ws[2][BN * BK];  // 2 x 16 KB
    __shared__ ushort_t Gs[2][BN * BK];  // 2 x 16 KB

    const int t    = threadIdx.x;
    const int wave = t >> 6;
    const int lane = t & 63;
    const int wm   = (wave >> 1) * 64;   // 0,64,128,192
    const int wn   = (wave & 1) * 64;    // 0,64

    // XCD-chunked swizzle: 256 blocks, 8 XCDs, 32 blocks/XCD = 2 by-rows x 16 bx.
    const int bid = blockIdx.y * 16 + blockIdx.x;
    const int swz = (bid & 7) * 32 + (bid >> 3);
    const int by  = swz >> 4;   // M tile (0..15)
    const int bx  = swz & 15;   // N tile (0..15)

    const int fr   = lane & 15;    // fragment row
    const int quad = lane >> 4;    // k-granule select (0..3)

    f32x4 accB[4][4] = {};
    f32x4 accP[4][4] = {};

    // --- staging addressing ---
    // A: 2048 slots of 16B (4 issues/thread). W/G: 1024 slots (2 issues each).
    // slot s: row = s>>3, fetched granule q' = (s&7) ^ (row&7)
    const ushort_t* gA[4]; int dA[4];
#pragma unroll
    for (int i = 0; i < 4; ++i) {
        int s   = i * 512 + t;
        int row = s >> 3;
        int q   = ((s & 7) ^ (row & 7)) * 8;
        gA[i] = xb + (size_t)(by * BM + row) * Kdim + q;
        dA[i] = (i * 512 + wave * 64) * 8;   // wave-uniform base; HW adds lane*16B
    }
    const ushort_t* gW[2]; const ushort_t* gG[2]; int dW[2];
#pragma unroll
    for (int i = 0; i < 2; ++i) {
        int s   = i * 512 + t;
        int row = s >> 3;
        int q   = ((s & 7) ^ (row & 7)) * 8;
        gW[i] = wb + (size_t)(bx * BN + row) * Kdim + q;
        gG[i] = gb + (size_t)(bx * BN + row) * Kdim + q;
        dW[i] = (i * 512 + wave * 64) * 8;
    }

    // single-buffered fragment regs (R8 budget; R10's ping-pong spilled)
    short8 af[4], wf[2], gf[2];

#define GLDS(g, l) __builtin_amdgcn_global_load_lds(GPTR(g), LPTR(l), 16, 0, 0)

    // staging spread: P0 {A0,A1,W0}, P1 {A2,A3,G0}, P2 {W1,G1}, P3 {}
#define STAGE_P0(B, K0) do {                                                      \
    GLDS(gA[0] + (K0), &As[B][dA[0]]);                                            \
    GLDS(gA[1] + (K0), &As[B][dA[1]]);                                            \
    GLDS(gW[0] + (K0), &Ws[B][dW[0]]);                                            \
} while (0)
#define STAGE_P1(B, K0) do {                                                      \
    GLDS(gA[2] + (K0), &As[B][dA[2]]);                                            \
    GLDS(gA[3] + (K0), &As[B][dA[3]]);                                            \
    GLDS(gG[0] + (K0), &Gs[B][dW[0]]);                                            \
} while (0)
#define STAGE_P2(B, K0) do {                                                      \
    GLDS(gW[1] + (K0), &Ws[B][dW[1]]);                                            \
    GLDS(gG[1] + (K0), &Gs[B][dW[1]]);                                            \
} while (0)

#define KC(J) ((((J) * 4 + quad) ^ (fr & 7)) * 8)

    // 4 A-fragment reads for k-half J
#define RD_AF(B, J) do {                                                          \
    const int kc_ = KC(J);                                                        \
    _Pragma("unroll")                                                             \
    for (int mt = 0; mt < 4; ++mt)                                                \
        af[mt] = *(const short8*)(&As[B][(wm + mt * 16 + fr) * BK + kc_]);        \
} while (0)

    // 2 W + 2 G fragment reads for (J, nt-half H)
#define RD_WG(B, J, H) do {                                                       \
    const int kc_ = KC(J);                                                        \
    _Pragma("unroll")                                                             \
    for (int i = 0; i < 2; ++i) {                                                 \
        const int nt = (H) * 2 + i;                                               \
        wf[i] = *(const short8*)(&Ws[B][(wn + nt * 16 + fr) * BK + kc_]);         \
        gf[i] = *(const short8*)(&Gs[B][(wn + nt * 16 + fr) * BK + kc_]);         \
    }                                                                             \
} while (0)

    // 16-MFMA cluster for nt-half H (per-acc update order identical R7-R10)
#define MFMA16(H) do {                                                            \
    __builtin_amdgcn_s_setprio(1);                                                \
    _Pragma("unroll")                                                             \
    for (int mt = 0; mt < 4; ++mt) {                                              \
        _Pragma("unroll")                                                         \
        for (int i = 0; i < 2; ++i) {                                             \
            const int nt = (H) * 2 + i;                                           \
            accB[mt][nt] = __builtin_amdgcn_mfma_f32_16x16x32_bf16(               \
                af[mt], wf[i], accB[mt][nt], 0, 0, 0);                            \
            accP[mt][nt] = __builtin_amdgcn_mfma_f32_16x16x32_bf16(               \
                af[mt], gf[i], accP[mt][nt], 0, 0, 0);                            \
        }                                                                         \
    }                                                                             \
    __builtin_amdgcn_s_setprio(0);                                                \
} while (0)

#define BARRIER() __builtin_amdgcn_s_barrier()
    // rule-18: exactly ONE sched fence after lgkmcnt(0) so MFMA can't hoist
#define LGKM0() do {                                                              \
    asm volatile("s_waitcnt lgkmcnt(0)" ::: "memory");                            \
    __builtin_amdgcn_sched_barrier(0);                                            \
} while (0)
#define VMCNT0() asm volatile("s_waitcnt vmcnt(0)" ::: "memory")

    // One K-tile on buffer B, m201 phase discipline (2 barriers/phase).
    // P3's vmcnt(0): last staging pair issued at P2 start -> >=1 phase
    // (~1000cy) of cover; its barrier doubles as the publish of B^1.
#define KTILE(B, K0NEXT) do {                                                     \
    /* P0 */                                                                      \
    RD_AF(B, 0); RD_WG(B, 0, 0);                                                  \
    STAGE_P0(B ^ 1, K0NEXT);                                                      \
    BARRIER(); LGKM0(); MFMA16(0); BARRIER();                                     \
    /* P1 */                                                                      \
    RD_WG(B, 0, 1);                                                               \
    STAGE_P1(B ^ 1, K0NEXT);                                                      \
    BARRIER(); LGKM0(); MFMA16(1); BARRIER();                                     \
    /* P2 */                                                                      \
    RD_AF(B, 1); RD_WG(B, 1, 0);                                                  \
    STAGE_P2(B ^ 1, K0NEXT);                                                      \
    BARRIER(); LGKM0(); MFMA16(0); BARRIER();                                     \
    /* P3 */                                                                      \
    RD_WG(B, 1, 1);                                                               \
    VMCNT0();                                                                     \
    BARRIER(); LGKM0(); MFMA16(1); BARRIER();                                     \
} while (0)

    // Last tile: no staging, no vmcnt (nothing outstanding), no final barrier.
#define KTILE_LAST(B) do {                                                        \
    RD_AF(B, 0); RD_WG(B, 0, 0);                                                  \
    BARRIER(); LGKM0(); MFMA16(0); BARRIER();                                     \
    RD_WG(B, 0, 1);                                                               \
    BARRIER(); LGKM0(); MFMA16(1); BARRIER();                                     \
    RD_AF(B, 1); RD_WG(B, 1, 0);                                                  \
    BARRIER(); LGKM0(); MFMA16(0); BARRIER();                                     \
    RD_WG(B, 1, 1);                                                               \
    LGKM0(); MFMA16(1);                                                           \
} while (0)

    // prologue: stage tile 0 into buf0 (full 8-load burst, one-time), publish
    STAGE_P0(0, 0); STAGE_P1(0, 0); STAGE_P2(0, 0);
    VMCNT0();
    BARRIER();

#pragma unroll 1
    for (int t2 = 0; t2 < NT - 2; t2 += 2) {
        KTILE(0, (t2 + 1) * BK);
        KTILE(1, (t2 + 2) * BK);
    }
    KTILE(0, (NT - 1) * BK);   // tile 30 stages tile 31
    KTILE_LAST(1);             // tile 31

#undef GLDS
#undef STAGE_P0
#undef STAGE_P1
#undef STAGE_P2
#undef RD_AF
#undef RD_WG
#undef MFMA16
#undef KTILE
#undef KTILE_LAST
#undef KC
#undef VMCNT0
#undef LGKM0
#undef BARRIER

    // --- epilogue: out = base + bias[n] - lr[m]*(pert + bgrad[n]) ---
    // C/D layout: col = lane&15, row = quad*4 + reg  (verified R2-R10)
    const int col = fr;
    const int gmb = by * BM + wm;
    const int gnb = bx * BN + wn;

    float lrv[4][4];
#pragma unroll
    for (int mt = 0; mt < 4; ++mt)
#pragma unroll
        for (int i = 0; i < 4; ++i)
            lrv[mt][i] = lr[gmb + mt * 16 + quad * 4 + i];

#pragma unroll
    for (int nt = 0; nt < 4; ++nt) {
        const int gn = gnb + nt * 16 + col;
        const float bn = bias[gn];
        const float bg = bgrad[gn];
#pragma unroll
        for (int mt = 0; mt < 4; ++mt) {
#pragma unroll
            for (int i = 0; i < 4; ++i) {
                const int gm = gmb + mt * 16 + quad * 4 + i;
                float v = accB[mt][nt][i] + bn - lrv[mt][i] * (accP[mt][nt][i] + bg);
                __builtin_nontemporal_store(v, out + (size_t)gm * Ndim + gn);
            }
        }
    }
}

extern "C" void kernel_launch(void* const* d_in, const int* in_sizes, int n_in,
                              void* d_out, int out_size, void* d_ws, size_t ws_size,
                              hipStream_t stream) {
    const float* x     = (const float*)d_in[0];  // [4096, 2048]
    const float* W     = (const float*)d_in[1];  // [2048, 2048]
    const float* bias  = (const float*)d_in[2];  // [2048]
    const float* G     = (const float*)d_in[3];  // [2048, 2048]
    const float* bgrad = (const float*)d_in[4];  // [2048]
    const float* lr    = (const float*)d_in[5];  // [4096]
    float* out = (float*)d_out;

    const int nX = 4096 * 2048;
    const int nW = 2048 * 2048;

    ushort_t* xb = (ushort_t*)d_ws;
    ushort_t* wb = xb + nX;
    ushort_t* gb = wb + nW;

    const int uX = nX / 8, uW = nW / 8;
    const int totalU = uX + 2 * uW;               // 2,097,152
    cvt_all_kernel<<<totalU / 256, 256, 0, stream>>>(x, W, G, xb, wb, gb, uX, uW);

    dim3 grid(16, 16);   // N tiles x M tiles = 256 blocks = 1/CU
    fused_gemm_kernel<<<grid, 512, 0, stream>>>(xb, wb, gb, bias, bgrad, lr, out);
}

// Round 5
// 170.300 us; speedup vs baseline: 1.1158x; 1.0544x over previous
//
#include <hip/hip_runtime.h>

// OptimizedLinear: out = x@W^T + bias - lr[:,None]*(x@G^T + bias_grad)
// B=4096, IN=OUT=2048, fp32 in/out. bf16 MFMA fused dual-accumulator GEMM.
//
// Round 12: the untested quadrant — fine phases + counted vmcnt that NEVER
// drains in the main loop + 1.5-tile prefetch depth (m201/m218 faithful).
// Session table: R7 1ph/drain=72us, R8 2ph/counted=72, R9 4ph/drain=79,
// R11 4ph/near-drain=81 — exactly m218's "8ph-with-drain0 == 1ph; T3's
// gain IS T4". This round: K-half chunk ring, 4 LDS slots x 32KB; per
// phase {ds_reads; 2 global_load_lds; barrier; lgkmcnt(0)+1 fence;
// setprio(1); 16 MFMA; setprio(0); barrier}; boundary wait = vmcnt(8)
// with ~4 phases (~2800cy) of cover; drains only in the last 2 chunks.
// WAR: chunk c stages slot (c+3)&3 = chunk c-1's slot, whose reads were
// lgkm-drained + barrier-confirmed before chunk c began.
// Per-acc k-update order unchanged -> absmax exactly 0.03125.
//
// Lessons carried: granule-XOR layout conflict-free (R2-R11, BANK_CONFLICT
// =0); scattered per-wave A-loads poison drains (R6); frag ping-pong
// spills (R10, tripwire WRITE_SIZE >> 45MB); sched_barrier beyond rule-18
// minimum is poison (R9/R10 = m141); drain-0 anywhere in the main loop
// nullifies fine phases (R9/R11 = m218); occupancy not the lever (R4).

typedef unsigned short ushort_t;
typedef __attribute__((ext_vector_type(8))) short short8;       // 8 bf16 = 4 VGPR
typedef __attribute__((ext_vector_type(8))) unsigned short ushort8;
typedef __attribute__((ext_vector_type(4))) float f32x4;

#define GPTR(p) ((const __attribute__((address_space(1))) void*)(p))
#define LPTR(p) ((__attribute__((address_space(3))) void*)(p))

static constexpr int Kdim = 2048;
static constexpr int Ndim = 2048;
static constexpr int BM   = 256;
static constexpr int BN   = 128;
static constexpr int CH   = 32;          // chunk K-depth (K-half of BK=64)
static constexpr int NCH  = Kdim / CH;   // 64 chunks

__device__ __forceinline__ unsigned short f2bf(float f) {
    union { float f; unsigned u; } c; c.f = f;
    unsigned u = c.u;
    unsigned r = (u + 0x7fffu + ((u >> 16) & 1u)) >> 16;  // RNE
    return (unsigned short)r;
}

// One launch converts x (uX ushort8-units), W (uW), G (uW). Unit = 8 elems.
__global__ void cvt_all_kernel(const float* __restrict__ x,
                               const float* __restrict__ W,
                               const float* __restrict__ G,
                               ushort_t* __restrict__ xb,
                               ushort_t* __restrict__ wb,
                               ushort_t* __restrict__ gb,
                               int uX, int uW) {
    int u = blockIdx.x * blockDim.x + threadIdx.x;
    const float* src; ushort_t* dst;
    if (u < uX)            { src = x; dst = xb; }
    else if (u < uX + uW)  { src = W; dst = wb; u -= uX; }
    else                   { src = G; dst = gb; u -= uX + uW; }
    int i = u * 8;
    float4 a = *(const float4*)(src + i);
    float4 b = *(const float4*)(src + i + 4);
    ushort8 r;
    r[0] = f2bf(a.x); r[1] = f2bf(a.y); r[2] = f2bf(a.z); r[3] = f2bf(a.w);
    r[4] = f2bf(b.x); r[5] = f2bf(b.y); r[6] = f2bf(b.z); r[7] = f2bf(b.w);
    *(ushort8*)(dst + i) = r;
}

// ---- fused dual GEMM, 256x128 tile, chunk-ring pipeline, 8 waves ----
// 512 threads = 8 waves (4 M x 2 N), each wave 64x64 = 4x4 MFMA tiles, dual
// acc. LDS: ring of 4 chunk-slots; chunk = K-half: A 256x32 (16KB) +
// W 128x32 (8KB) + G (8KB) = 32KB/slot, 128KB total (1 block/CU).
// Granule (row r, g=k/8) of a chunk lives at position g ^ (r&3) (4-granule
// rows); swizzle applied on the GLOBAL fetch address (LDS dst is HW-forced
// to base + lane*16). Fragment read: addr = row*32 + (quad^(row&3))*8
// elems -> 8 bank-groups x 8 lanes = 2 lanes/bank = conflict-free (m136:
// 2-way is free; same family as the R2-R11 layout that measured 0).
__global__ __launch_bounds__(512, 2) void fused_gemm_kernel(
    const ushort_t* __restrict__ xb,   // [4096, 2048] bf16
    const ushort_t* __restrict__ wb,   // [2048, 2048] bf16
    const ushort_t* __restrict__ gb,   // [2048, 2048] bf16
    const float* __restrict__ bias,    // [2048]
    const float* __restrict__ bgrad,   // [2048]
    const float* __restrict__ lr,      // [4096]
    float* __restrict__ out)           // [4096, 2048] fp32
{
    // slot layout (ushort elems): A at +0 (8192), W at +8192 (4096), G at +12288
    __shared__ ushort_t lds[4 * 16384];  // 128 KB
#define AOFF(S) ((S) * 16384)
#define WOFF(S) ((S) * 16384 + 8192)
#define GOFF(S) ((S) * 16384 + 12288)

    const int t    = threadIdx.x;
    const int wave = t >> 6;
    const int lane = t & 63;
    const int wm   = (wave >> 1) * 64;   // 0,64,128,192
    const int wn   = (wave & 1) * 64;    // 0,64

    // XCD-chunked swizzle: 256 blocks, 8 XCDs, 32 blocks/XCD = 2 by-rows x 16 bx.
    const int bid = blockIdx.y * 16 + blockIdx.x;
    const int swz = (bid & 7) * 32 + (bid >> 3);
    const int by  = swz >> 4;   // M tile (0..15)
    const int bx  = swz & 15;   // N tile (0..15)

    const int fr   = lane & 15;    // fragment row
    const int quad = lane >> 4;    // k-granule select (0..3)

    f32x4 accB[4][4] = {};
    f32x4 accP[4][4] = {};

    // --- staging addressing (per chunk) ---
    // A: 1024 granules of 16B, 2 issues/thread. W/G: 512 granules, 1 each.
    // slot s: row = s>>2, fetched granule g = (s&2..0: s&3) ^ (row&3)
    const ushort_t* srcA[2]; int dstA[2];
#pragma unroll
    for (int i = 0; i < 2; ++i) {
        int s   = i * 512 + t;
        int row = s >> 2;
        int g   = (s & 3) ^ (row & 3);
        srcA[i] = xb + (size_t)(by * BM + row) * Kdim + g * 8;
        dstA[i] = (i * 512 + wave * 64) * 8;   // wave-uniform; HW adds lane*16B
    }
    const int rowW = t >> 2;
    const int gWsw = (t & 3) ^ (rowW & 3);
    const ushort_t* srcW = wb + (size_t)(bx * BN + rowW) * Kdim + gWsw * 8;
    const ushort_t* srcG = gb + (size_t)(bx * BN + rowW) * Kdim + gWsw * 8;
    const int dstWG = wave * 512;              // wave*64 granules * 8 elems

    // per-thread ds_read bases (16-bit ds offset immediates cover the rest)
    const int qsel    = (quad ^ (fr & 3)) * 8;
    const int aRdBase = (wm + fr) * CH + qsel;
    const int wRdBase = (wn + fr) * CH + qsel;

    short8 af[4], wf[2], gf[2];

#define GLDS(g, l) __builtin_amdgcn_global_load_lds(GPTR(g), LPTR(l), 16, 0, 0)

#define STAGE_A(SS, KOFF) do {                                                    \
    GLDS(srcA[0] + (KOFF), &lds[AOFF(SS) + dstA[0]]);                             \
    GLDS(srcA[1] + (KOFF), &lds[AOFF(SS) + dstA[1]]);                             \
} while (0)
#define STAGE_WG(SS, KOFF) do {                                                   \
    GLDS(srcW + (KOFF), &lds[WOFF(SS) + dstWG]);                                  \
    GLDS(srcG + (KOFF), &lds[GOFF(SS) + dstWG]);                                  \
} while (0)

    // 4 A-fragment reads for chunk in slot S (held across both phases)
#define RD_A(S) do {                                                              \
    _Pragma("unroll")                                                             \
    for (int mt = 0; mt < 4; ++mt)                                                \
        af[mt] = *(const short8*)(&lds[AOFF(S) + aRdBase + mt * (16 * CH)]);      \
} while (0)

    // 2 W + 2 G fragment reads for nt-half H
#define RD_WG(S, H) do {                                                          \
    _Pragma("unroll")                                                             \
    for (int i = 0; i < 2; ++i) {                                                 \
        const int nt = (H) * 2 + i;                                               \
        wf[i] = *(const short8*)(&lds[WOFF(S) + wRdBase + nt * (16 * CH)]);       \
        gf[i] = *(const short8*)(&lds[GOFF(S) + wRdBase + nt * (16 * CH)]);       \
    }                                                                             \
} while (0)

    // 16-MFMA cluster for nt-half H (per-acc k-order identical to R7-R11)
#define MFMA16(H) do {                                                            \
    __builtin_amdgcn_s_setprio(1);                                                \
    _Pragma("unroll")                                                             \
    for (int mt = 0; mt < 4; ++mt) {                                              \
        _Pragma("unroll")                                                         \
        for (int i = 0; i < 2; ++i) {                                             \
            const int nt = (H) * 2 + i;                                           \
            accB[mt][nt] = __builtin_amdgcn_mfma_f32_16x16x32_bf16(               \
                af[mt], wf[i], accB[mt][nt], 0, 0, 0);                            \
            accP[mt][nt] = __builtin_amdgcn_mfma_f32_16x16x32_bf16(               \
                af[mt], gf[i], accP[mt][nt], 0, 0, 0);                            \
        }                                                                         \
    }                                                                             \
    __builtin_amdgcn_s_setprio(0);                                                \
} while (0)

#define BARRIER() __builtin_amdgcn_s_barrier()
    // rule-18: exactly ONE sched fence after lgkmcnt(0) so MFMA can't hoist
#define LGKM0() do {                                                              \
    asm volatile("s_waitcnt lgkmcnt(0)" ::: "memory");                            \
    __builtin_amdgcn_sched_barrier(0);                                            \
} while (0)
#define WAITVM(N) asm volatile("s_waitcnt vmcnt(" #N ")" ::: "memory")

    // One chunk (K=32) in slot S. 2 phases; 2 gloads/phase when staging.
    // WAITSTMT at the chunk boundary guarantees chunk c+1 landed; in steady
    // state the 8 outstanding younger loads (chunks c+2, c+3) stay in
    // flight -> never drains. The post-MFMA barrier publishes c+1.
#define CHUNK(S, KOFF, DOSTG, SS, SKOFF, WAITSTMT) do {                           \
    RD_A(S); RD_WG(S, 0);                                                         \
    if (DOSTG) STAGE_A(SS, SKOFF);                                                \
    BARRIER(); LGKM0(); MFMA16(0); BARRIER();                                     \
    RD_WG(S, 1);                                                                  \
    if (DOSTG) STAGE_WG(SS, SKOFF);                                               \
    WAITSTMT;                                                                     \
    BARRIER(); LGKM0(); MFMA16(1); BARRIER();                                     \
} while (0)

    // prologue: stage chunks 0,1,2 (slots 0,1,2); wait for chunk 0 only
    STAGE_A(0, 0);      STAGE_WG(0, 0);
    STAGE_A(1, CH);     STAGE_WG(1, CH);
    STAGE_A(2, 2 * CH); STAGE_WG(2, 2 * CH);
    WAITVM(8);
    BARRIER();

#pragma unroll 1
    for (int c = 0; c < NCH - 4; c += 4) {        // c = 0,4,...,56
        const int kb = c * CH;
        CHUNK(0, kb,          1, 3, kb + 3 * CH, WAITVM(8));
        CHUNK(1, kb + CH,     1, 0, kb + 4 * CH, WAITVM(8));
        CHUNK(2, kb + 2 * CH, 1, 1, kb + 5 * CH, WAITVM(8));
        CHUNK(3, kb + 3 * CH, 1, 2, kb + 6 * CH, WAITVM(8));
    }
    // epilogue: chunks 60..63 (only 60 still stages -> chunk 63)
    CHUNK(0, 60 * CH, 1, 3, 63 * CH, WAITVM(8));
    CHUNK(1, 61 * CH, 0, 0, 0,       WAITVM(4));
    CHUNK(2, 62 * CH, 0, 0, 0,       WAITVM(0));
    // chunk 63 (slot 3): last — no staging, no boundary wait
    RD_A(3); RD_WG(3, 0);
    BARRIER(); LGKM0(); MFMA16(0); BARRIER();
    RD_WG(3, 1);
    LGKM0(); MFMA16(1);

#undef GLDS
#undef STAGE_A
#undef STAGE_WG
#undef RD_A
#undef RD_WG
#undef MFMA16
#undef CHUNK
#undef WAITVM
#undef LGKM0
#undef BARRIER
#undef AOFF
#undef WOFF
#undef GOFF

    // --- epilogue: out = base + bias[n] - lr[m]*(pert + bgrad[n]) ---
    // C/D layout: col = lane&15, row = quad*4 + reg  (verified R2-R11)
    const int col = fr;
    const int gmb = by * BM + wm;
    const int gnb = bx * BN + wn;

    float lrv[4][4];
#pragma unroll
    for (int mt = 0; mt < 4; ++mt)
#pragma unroll
        for (int i = 0; i < 4; ++i)
            lrv[mt][i] = lr[gmb + mt * 16 + quad * 4 + i];

#pragma unroll
    for (int nt = 0; nt < 4; ++nt) {
        const int gn = gnb + nt * 16 + col;
        const float bn = bias[gn];
        const float bg = bgrad[gn];
#pragma unroll
        for (int mt = 0; mt < 4; ++mt) {
#pragma unroll
            for (int i = 0; i < 4; ++i) {
                const int gm = gmb + mt * 16 + quad * 4 + i;
                float v = accB[mt][nt][i] + bn - lrv[mt][i] * (accP[mt][nt][i] + bg);
                __builtin_nontemporal_store(v, out + (size_t)gm * Ndim + gn);
            }
        }
    }
}

extern "C" void kernel_launch(void* const* d_in, const int* in_sizes, int n_in,
                              void* d_out, int out_size, void* d_ws, size_t ws_size,
                              hipStream_t stream) {
    const float* x     = (const float*)d_in[0];  // [4096, 2048]
    const float* W     = (const float*)d_in[1];  // [2048, 2048]
    const float* bias  = (const float*)d_in[2];  // [2048]
    const float* G     = (const float*)d_in[3];  // [2048, 2048]
    const float* bgrad = (const float*)d_in[4];  // [2048]
    const float* lr    = (const float*)d_in[5];  // [4096]
    float* out = (float*)d_out;

    const int nX = 4096 * 2048;
    const int nW = 2048 * 2048;

    ushort_t* xb = (ushort_t*)d_ws;
    ushort_t* wb = xb + nX;
    ushort_t* gb = wb + nW;

    const int uX = nX / 8, uW = nW / 8;
    const int totalU = uX + 2 * uW;               // 2,097,152
    cvt_all_kernel<<<totalU / 256, 256, 0, stream>>>(x, W, G, xb, wb, gb, uX, uW);

    dim3 grid(16, 16);   // N tiles x M tiles = 256 blocks = 1/CU
    fused_gemm_kernel<<<grid, 512, 0, stream>>>(xb, wb, gb, bias, bgrad, lr, out);
}

// Round 6
// 169.600 us; speedup vs baseline: 1.1204x; 1.0041x over previous
//
#include <hip/hip_runtime.h>

// OptimizedLinear: out = x@W^T + bias - lr[:,None]*(x@G^T + bias_grad)
// B=4096, IN=OUT=2048, fp32 in/out. bf16 MFMA fused dual-accumulator GEMM.
//
// Round 13: R12 chunk-ring pipeline UNCHANGED; fix its bank conflicts.
// R12 measured SQ_LDS_BANK_CONFLICT = 6.29M = exactly 4 extra cyc on each
// of 192 ds_read_b128 per K-tile per CU (= 14% of kernel time): the CH=32
// swizzle g^(r&3) collapses rows {0,4,8,12} of a quarter-wave into one
// bank-group (4-way conflict). Fix: f(r) = (r>>1)&3. Read bank-group =
// 4*(r&1) + (quad ^ ((r>>1)&3)) -> fr=0..15 covers all 8 groups exactly
// twice (rows r/r+8, 2 slots per group) = the same quarter-wave property
// as the R2-R11 BK=64 layout that measured 0 conflicts. Swizzle applied
// on BOTH the staging source address and the read address (rule 21).
// Layout-only change; per-acc k-order unchanged -> absmax 0.03125.
//
// Falsification: conflicts ~0 but gemm >= 70us -> fine-schedule family is
// null at this geometry; pivot to folding cvt into the GEMM.
//
// Lessons carried: scattered per-wave A-loads poison drains (R6); frag
// ping-pong spills (R10, tripwire WRITE_SIZE >> 45MB); sched_barrier
// beyond rule-18 minimum is poison (R9/R10 = m141); drain-0 in the main
// loop nullifies fine phases (R9/R11 = m218); conflict math: 6.3M counts
// = 768 cyc/K-tile/CU = 10us (R12); occupancy not the lever (R4).

typedef unsigned short ushort_t;
typedef __attribute__((ext_vector_type(8))) short short8;       // 8 bf16 = 4 VGPR
typedef __attribute__((ext_vector_type(8))) unsigned short ushort8;
typedef __attribute__((ext_vector_type(4))) float f32x4;

#define GPTR(p) ((const __attribute__((address_space(1))) void*)(p))
#define LPTR(p) ((__attribute__((address_space(3))) void*)(p))

static constexpr int Kdim = 2048;
static constexpr int Ndim = 2048;
static constexpr int BM   = 256;
static constexpr int BN   = 128;
static constexpr int CH   = 32;          // chunk K-depth
static constexpr int NCH  = Kdim / CH;   // 64 chunks

__device__ __forceinline__ unsigned short f2bf(float f) {
    union { float f; unsigned u; } c; c.f = f;
    unsigned u = c.u;
    unsigned r = (u + 0x7fffu + ((u >> 16) & 1u)) >> 16;  // RNE
    return (unsigned short)r;
}

// One launch converts x (uX ushort8-units), W (uW), G (uW). Unit = 8 elems.
__global__ void cvt_all_kernel(const float* __restrict__ x,
                               const float* __restrict__ W,
                               const float* __restrict__ G,
                               ushort_t* __restrict__ xb,
                               ushort_t* __restrict__ wb,
                               ushort_t* __restrict__ gb,
                               int uX, int uW) {
    int u = blockIdx.x * blockDim.x + threadIdx.x;
    const float* src; ushort_t* dst;
    if (u < uX)            { src = x; dst = xb; }
    else if (u < uX + uW)  { src = W; dst = wb; u -= uX; }
    else                   { src = G; dst = gb; u -= uX + uW; }
    int i = u * 8;
    float4 a = *(const float4*)(src + i);
    float4 b = *(const float4*)(src + i + 4);
    ushort8 r;
    r[0] = f2bf(a.x); r[1] = f2bf(a.y); r[2] = f2bf(a.z); r[3] = f2bf(a.w);
    r[4] = f2bf(b.x); r[5] = f2bf(b.y); r[6] = f2bf(b.z); r[7] = f2bf(b.w);
    *(ushort8*)(dst + i) = r;
}

// ---- fused dual GEMM, 256x128 tile, chunk-ring pipeline, 8 waves ----
// 512 threads = 8 waves (4 M x 2 N), each wave 64x64 = 4x4 MFMA tiles, dual
// acc. LDS: ring of 4 chunk-slots; chunk = K-half: A 256x32 (16KB) +
// W 128x32 (8KB) + G (8KB) = 32KB/slot, 128KB total (1 block/CU).
// Granule (row r, g=k/8) of a chunk lives at position g ^ ((r>>1)&3);
// swizzle applied on the GLOBAL fetch address (LDS dst is HW-forced to
// base + lane*16). Fragment read: byte = r*64 + ((quad^((r>>1)&3))*16)
// -> bank-group = 4*(r&1) + (quad^((r>>1)&3)): all 8 groups x2 per
// quarter-wave = conflict-free (R2-R11 property, rederived for CH=32).
__global__ __launch_bounds__(512, 2) void fused_gemm_kernel(
    const ushort_t* __restrict__ xb,   // [4096, 2048] bf16
    const ushort_t* __restrict__ wb,   // [2048, 2048] bf16
    const ushort_t* __restrict__ gb,   // [2048, 2048] bf16
    const float* __restrict__ bias,    // [2048]
    const float* __restrict__ bgrad,   // [2048]
    const float* __restrict__ lr,      // [4096]
    float* __restrict__ out)           // [4096, 2048] fp32
{
    // slot layout (ushort elems): A at +0 (8192), W at +8192 (4096), G at +12288
    __shared__ ushort_t lds[4 * 16384];  // 128 KB
#define AOFF(S) ((S) * 16384)
#define WOFF(S) ((S) * 16384 + 8192)
#define GOFF(S) ((S) * 16384 + 12288)

    const int t    = threadIdx.x;
    const int wave = t >> 6;
    const int lane = t & 63;
    const int wm   = (wave >> 1) * 64;   // 0,64,128,192
    const int wn   = (wave & 1) * 64;    // 0,64

    // XCD-chunked swizzle: 256 blocks, 8 XCDs, 32 blocks/XCD = 2 by-rows x 16 bx.
    const int bid = blockIdx.y * 16 + blockIdx.x;
    const int swz = (bid & 7) * 32 + (bid >> 3);
    const int by  = swz >> 4;   // M tile (0..15)
    const int bx  = swz & 15;   // N tile (0..15)

    const int fr   = lane & 15;    // fragment row
    const int quad = lane >> 4;    // k-granule select (0..3)

    f32x4 accB[4][4] = {};
    f32x4 accP[4][4] = {};

    // --- staging addressing (per chunk) ---
    // A: 1024 granules of 16B, 2 issues/thread. W/G: 512 granules, 1 each.
    // slot s: row = s>>2, fetched granule g = (s&3) ^ ((row>>1)&3)
    const ushort_t* srcA[2]; int dstA[2];
#pragma unroll
    for (int i = 0; i < 2; ++i) {
        int s   = i * 512 + t;
        int row = s >> 2;
        int g   = (s & 3) ^ ((row >> 1) & 3);
        srcA[i] = xb + (size_t)(by * BM + row) * Kdim + g * 8;
        dstA[i] = (i * 512 + wave * 64) * 8;   // wave-uniform; HW adds lane*16B
    }
    const int rowW = t >> 2;
    const int gWsw = (t & 3) ^ ((rowW >> 1) & 3);
    const ushort_t* srcW = wb + (size_t)(bx * BN + rowW) * Kdim + gWsw * 8;
    const ushort_t* srcG = gb + (size_t)(bx * BN + rowW) * Kdim + gWsw * 8;
    const int dstWG = wave * 512;              // wave*64 granules * 8 elems

    // per-thread ds_read bases; f(r) = (r>>1)&3 depends only on fr (wm, wn,
    // mt*16, nt*16 are multiples of 16 -> drop out of (r>>1)&3)
    const int qsel    = (quad ^ ((fr >> 1) & 3)) * 8;
    const int aRdBase = (wm + fr) * CH + qsel;
    const int wRdBase = (wn + fr) * CH + qsel;

    short8 af[4], wf[2], gf[2];

#define GLDS(g, l) __builtin_amdgcn_global_load_lds(GPTR(g), LPTR(l), 16, 0, 0)

#define STAGE_A(SS, KOFF) do {                                                    \
    GLDS(srcA[0] + (KOFF), &lds[AOFF(SS) + dstA[0]]);                             \
    GLDS(srcA[1] + (KOFF), &lds[AOFF(SS) + dstA[1]]);                             \
} while (0)
#define STAGE_WG(SS, KOFF) do {                                                   \
    GLDS(srcW + (KOFF), &lds[WOFF(SS) + dstWG]);                                  \
    GLDS(srcG + (KOFF), &lds[GOFF(SS) + dstWG]);                                  \
} while (0)

    // 4 A-fragment reads for chunk in slot S (held across both phases)
#define RD_A(S) do {                                                              \
    _Pragma("unroll")                                                             \
    for (int mt = 0; mt < 4; ++mt)                                                \
        af[mt] = *(const short8*)(&lds[AOFF(S) + aRdBase + mt * (16 * CH)]);      \
} while (0)

    // 2 W + 2 G fragment reads for nt-half H
#define RD_WG(S, H) do {                                                          \
    _Pragma("unroll")                                                             \
    for (int i = 0; i < 2; ++i) {                                                 \
        const int nt = (H) * 2 + i;                                               \
        wf[i] = *(const short8*)(&lds[WOFF(S) + wRdBase + nt * (16 * CH)]);       \
        gf[i] = *(const short8*)(&lds[GOFF(S) + wRdBase + nt * (16 * CH)]);       \
    }                                                                             \
} while (0)

    // 16-MFMA cluster for nt-half H (per-acc k-order identical to R7-R12)
#define MFMA16(H) do {                                                            \
    __builtin_amdgcn_s_setprio(1);                                                \
    _Pragma("unroll")                                                             \
    for (int mt = 0; mt < 4; ++mt) {                                              \
        _Pragma("unroll")                                                         \
        for (int i = 0; i < 2; ++i) {                                             \
            const int nt = (H) * 2 + i;                                           \
            accB[mt][nt] = __builtin_amdgcn_mfma_f32_16x16x32_bf16(               \
                af[mt], wf[i], accB[mt][nt], 0, 0, 0);                            \
            accP[mt][nt] = __builtin_amdgcn_mfma_f32_16x16x32_bf16(               \
                af[mt], gf[i], accP[mt][nt], 0, 0, 0);                            \
        }                                                                         \
    }                                                                             \
    __builtin_amdgcn_s_setprio(0);                                                \
} while (0)

#define BARRIER() __builtin_amdgcn_s_barrier()
    // rule-18: exactly ONE sched fence after lgkmcnt(0) so MFMA can't hoist
#define LGKM0() do {                                                              \
    asm volatile("s_waitcnt lgkmcnt(0)" ::: "memory");                            \
    __builtin_amdgcn_sched_barrier(0);                                            \
} while (0)
#define WAITVM(N) asm volatile("s_waitcnt vmcnt(" #N ")" ::: "memory")

    // One chunk (K=32) in slot S. 2 phases; 2 gloads/phase when staging.
    // WAITSTMT at the chunk boundary guarantees chunk c+1 landed; in steady
    // state the 8 outstanding younger loads (chunks c+2, c+3) stay in
    // flight -> never drains. The post-MFMA barrier publishes c+1.
#define CHUNK(S, KOFF, DOSTG, SS, SKOFF, WAITSTMT) do {                           \
    RD_A(S); RD_WG(S, 0);                                                         \
    if (DOSTG) STAGE_A(SS, SKOFF);                                                \
    BARRIER(); LGKM0(); MFMA16(0); BARRIER();                                     \
    RD_WG(S, 1);                                                                  \
    if (DOSTG) STAGE_WG(SS, SKOFF);                                               \
    WAITSTMT;                                                                     \
    BARRIER(); LGKM0(); MFMA16(1); BARRIER();                                     \
} while (0)

    // prologue: stage chunks 0,1,2 (slots 0,1,2); wait for chunk 0 only
    STAGE_A(0, 0);      STAGE_WG(0, 0);
    STAGE_A(1, CH);     STAGE_WG(1, CH);
    STAGE_A(2, 2 * CH); STAGE_WG(2, 2 * CH);
    WAITVM(8);
    BARRIER();

#pragma unroll 1
    for (int c = 0; c < NCH - 4; c += 4) {        // c = 0,4,...,56
        const int kb = c * CH;
        CHUNK(0, kb,          1, 3, kb + 3 * CH, WAITVM(8));
        CHUNK(1, kb + CH,     1, 0, kb + 4 * CH, WAITVM(8));
        CHUNK(2, kb + 2 * CH, 1, 1, kb + 5 * CH, WAITVM(8));
        CHUNK(3, kb + 3 * CH, 1, 2, kb + 6 * CH, WAITVM(8));
    }
    // epilogue: chunks 60..63 (only 60 still stages -> chunk 63)
    CHUNK(0, 60 * CH, 1, 3, 63 * CH, WAITVM(8));
    CHUNK(1, 61 * CH, 0, 0, 0,       WAITVM(4));
    CHUNK(2, 62 * CH, 0, 0, 0,       WAITVM(0));
    // chunk 63 (slot 3): last — no staging, no boundary wait
    RD_A(3); RD_WG(3, 0);
    BARRIER(); LGKM0(); MFMA16(0); BARRIER();
    RD_WG(3, 1);
    LGKM0(); MFMA16(1);

#undef GLDS
#undef STAGE_A
#undef STAGE_WG
#undef RD_A
#undef RD_WG
#undef MFMA16
#undef CHUNK
#undef WAITVM
#undef LGKM0
#undef BARRIER
#undef AOFF
#undef WOFF
#undef GOFF

    // --- epilogue: out = base + bias[n] - lr[m]*(pert + bgrad[n]) ---
    // C/D layout: col = lane&15, row = quad*4 + reg  (verified R2-R12)
    const int col = fr;
    const int gmb = by * BM + wm;
    const int gnb = bx * BN + wn;

    float lrv[4][4];
#pragma unroll
    for (int mt = 0; mt < 4; ++mt)
#pragma unroll
        for (int i = 0; i < 4; ++i)
            lrv[mt][i] = lr[gmb + mt * 16 + quad * 4 + i];

#pragma unroll
    for (int nt = 0; nt < 4; ++nt) {
        const int gn = gnb + nt * 16 + col;
        const float bn = bias[gn];
        const float bg = bgrad[gn];
#pragma unroll
        for (int mt = 0; mt < 4; ++mt) {
#pragma unroll
            for (int i = 0; i < 4; ++i) {
                const int gm = gmb + mt * 16 + quad * 4 + i;
                float v = accB[mt][nt][i] + bn - lrv[mt][i] * (accP[mt][nt][i] + bg);
                __builtin_nontemporal_store(v, out + (size_t)gm * Ndim + gn);
            }
        }
    }
}

extern "C" void kernel_launch(void* const* d_in, const int* in_sizes, int n_in,
                              void* d_out, int out_size, void* d_ws, size_t ws_size,
                              hipStream_t stream) {
    const float* x     = (const float*)d_in[0];  // [4096, 2048]
    const float* W     = (const float*)d_in[1];  // [2048, 2048]
    const float* bias  = (const float*)d_in[2];  // [2048]
    const float* G     = (const float*)d_in[3];  // [2048, 2048]
    const float* bgrad = (const float*)d_in[4];  // [2048]
    const float* lr    = (const float*)d_in[5];  // [4096]
    float* out = (float*)d_out;

    const int nX = 4096 * 2048;
    const int nW = 2048 * 2048;

    ushort_t* xb = (ushort_t*)d_ws;
    ushort_t* wb = xb + nX;
    ushort_t* gb = wb + nW;

    const int uX = nX / 8, uW = nW / 8;
    const int totalU = uX + 2 * uW;               // 2,097,152
    cvt_all_kernel<<<totalU / 256, 256, 0, stream>>>(x, W, G, xb, wb, gb, uX, uW);

    dim3 grid(16, 16);   // N tiles x M tiles = 256 blocks = 1/CU
    fused_gemm_kernel<<<grid, 512, 0, stream>>>(xb, wb, gb, bias, bgrad, lr, out);
}